// Round 6
// baseline (309.634 us; speedup 1.0000x reference)
//
#include <hip/hip_runtime.h>

#define BATCH 8
#define CH 128
#define HH 128
#define WW 128
#define HWSZ 16384
#define NHEADS 8
#define DHEAD 2048

typedef short bf16x8 __attribute__((ext_vector_type(8)));
typedef short bf16x4v __attribute__((ext_vector_type(4)));
typedef float f32x4 __attribute__((ext_vector_type(4)));
typedef float f32x2 __attribute__((ext_vector_type(2)));
typedef _Float16 f16x8 __attribute__((ext_vector_type(8)));
typedef _Float16 f16x4 __attribute__((ext_vector_type(4)));

static __device__ inline unsigned short f2bf(float f) {
    unsigned u = __builtin_bit_cast(unsigned, f);
    u += 0x7fff + ((u >> 16) & 1);          // round-to-nearest-even
    return (unsigned short)(u >> 16);
}

// packed f32x2 -> bf16x2 (RNE), gfx950 has no builtin (T12) -> inline asm
static __device__ inline unsigned cvtpk(float lo, float hi) {
    unsigned r;
    asm("v_cvt_pk_bf16_f32 %0, %1, %2" : "=v"(r) : "v"(lo), "v"(hi));
    return r;
}

// ---------------- Kernel 0: build Toeplitz fragments for dwconv MFMA ----------
__global__ __launch_bounds__(256) void toeplitz_prep_kernel(
    const float* __restrict__ wq, const float* __restrict__ wk,
    const float* __restrict__ wv, _Float16* __restrict__ Tp)
{
    const int g = blockIdx.x * 256 + threadIdx.x;   // 128*27*64 = 221184
    const int c    = g / 1728;                      // 27*64
    const int rem  = g - c * 1728;
    const int m    = rem >> 6;
    const int lane = rem & 63;
    const int conv = m / 9;
    const int dy   = m - conv * 9;
    const float* w = (conv == 0) ? wq : ((conv == 1) ? wk : wv);
    const int j    = lane & 15;
    const int kb   = (lane >> 4) << 3;
    f16x8 h;
    #pragma unroll
    for (int e = 0; e < 8; ++e) {
        const int d = kb + e - j;
        h[e] = (d >= 0 && d <= 8) ? (_Float16)w[c * 81 + dy * 9 + d]
                                  : (_Float16)0.f;
    }
    *(f16x8*)&Tp[(size_t)g * 8] = h;
}

// ---------------- Kernel 1: depthwise 9x9 conv -> Q,K,V via MFMA Toeplitz -----
// launch_bounds(256,2): VGPR cap 256 so the 27 Toeplitz B-fragments stay
// register-resident (round-5 counters showed VGPR=88 -> compiler was
// re-loading all 27 from memory every t-iter; that was the latency wall).
__global__ __launch_bounds__(256, 2) void dwconv_qkv_mfma_kernel(
    const float* __restrict__ x,
    const float* __restrict__ bq, const float* __restrict__ bk,
    const float* __restrict__ bv,
    const _Float16* __restrict__ Tp,
    unsigned short* __restrict__ Qb, unsigned short* __restrict__ Kb,
    unsigned short* __restrict__ Vb)
{
    const int bc = blockIdx.x;
    const int b  = bc >> 7;
    const int c  = bc & (CH - 1);

    __shared__ _Float16 img[136][144];   // [y+4][x+4], zero halo, 39168 B

    const int tid  = threadIdx.x;
    const int wave = tid >> 6;
    const int lane = tid & 63;
    const int lx   = lane & 15;
    const int qd   = lane >> 4;

    f16x8 Btp[27];
    const _Float16* tp = Tp + (size_t)c * 13824 + (size_t)lane * 8;
    #pragma unroll
    for (int m = 0; m < 27; ++m)
        Btp[m] = *(const f16x8*)(tp + (size_t)m * 512);

    {
        f16x8 z = {0, 0, 0, 0, 0, 0, 0, 0};
        _Float16* flat = &img[0][0];
        for (int i = tid; i < 2448; i += 256)       // 136*144/8
            *(f16x8*)&flat[i * 8] = z;
    }
    __syncthreads();
    const float* xp = x + (size_t)bc * HWSZ;
    for (int i = tid; i < 4096; i += 256) {
        const float4 v = *(const float4*)&xp[i * 4];
        const int y  = i >> 5;
        const int xc = (i & 31) << 2;
        f16x4 h = {(_Float16)v.x, (_Float16)v.y, (_Float16)v.z, (_Float16)v.w};
        *(f16x4*)&img[y + 4][xc + 4] = h;
    }
    __syncthreads();

    const float bqv = bq[c], bkv = bk[c], bvv = bv[c];

    #pragma unroll 1
    for (int t = 0; t < 8; ++t) {
        const int sg = t * 4 + wave;                // 32 supergroups / block
        const int yg = sg >> 2;
        const int y0 = yg << 4;
        const int x0 = (sg & 3) << 5;

        f32x4 aq0 = {bqv, bqv, bqv, bqv}, aq1 = aq0;
        f32x4 ak0 = {bkv, bkv, bkv, bkv}, ak1 = ak0;
        f32x4 av0 = {bvv, bvv, bvv, bvv}, av1 = av0;

        const _Float16* rp = &img[y0 + lx][x0 + (qd << 3)];
        #pragma unroll
        for (int dy = 0; dy < 9; ++dy) {
            const f16x8 a0 = *(const f16x8*)rp;
            const f16x8 a1 = *(const f16x8*)(rp + 16);
            rp += 144;
            aq0 = __builtin_amdgcn_mfma_f32_16x16x32_f16(a0, Btp[dy],      aq0, 0, 0, 0);
            aq1 = __builtin_amdgcn_mfma_f32_16x16x32_f16(a1, Btp[dy],      aq1, 0, 0, 0);
            ak0 = __builtin_amdgcn_mfma_f32_16x16x32_f16(a0, Btp[9 + dy],  ak0, 0, 0, 0);
            ak1 = __builtin_amdgcn_mfma_f32_16x16x32_f16(a1, Btp[9 + dy],  ak1, 0, 0, 0);
            av0 = __builtin_amdgcn_mfma_f32_16x16x32_f16(a0, Btp[18 + dy], av0, 0, 0, 0);
            av1 = __builtin_amdgcn_mfma_f32_16x16x32_f16(a1, Btp[18 + dy], av1, 0, 0, 0);
        }

        // C layout: lane holds D[y = qd*4+r][x = lx]; t = (y&15)*128 + x, head = yg
        const size_t base = ((size_t)(b * 8 + yg) * CH + c) * DHEAD
                          + (size_t)(qd << 2) * WW + x0 + lx;
        #pragma unroll
        for (int rp2 = 0; rp2 < 4; rp2 += 2) {
            const unsigned pq0 = cvtpk(aq0[rp2], aq0[rp2 + 1]);
            const unsigned pq1 = cvtpk(aq1[rp2], aq1[rp2 + 1]);
            const unsigned pk0 = cvtpk(ak0[rp2], ak0[rp2 + 1]);
            const unsigned pk1 = cvtpk(ak1[rp2], ak1[rp2 + 1]);
            const unsigned pv0 = cvtpk(av0[rp2], av0[rp2 + 1]);
            const unsigned pv1 = cvtpk(av1[rp2], av1[rp2 + 1]);
            Qb[base + rp2 * WW]            = (unsigned short)pq0;
            Qb[base + (rp2 + 1) * WW]      = (unsigned short)(pq0 >> 16);
            Qb[base + rp2 * WW + 16]       = (unsigned short)pq1;
            Qb[base + (rp2 + 1) * WW + 16] = (unsigned short)(pq1 >> 16);
            Kb[base + rp2 * WW]            = (unsigned short)pk0;
            Kb[base + (rp2 + 1) * WW]      = (unsigned short)(pk0 >> 16);
            Kb[base + rp2 * WW + 16]       = (unsigned short)pk1;
            Kb[base + (rp2 + 1) * WW + 16] = (unsigned short)(pk1 >> 16);
            Vb[base + rp2 * WW]            = (unsigned short)pv0;
            Vb[base + (rp2 + 1) * WW]      = (unsigned short)(pv0 >> 16);
            Vb[base + rp2 * WW + 16]       = (unsigned short)pv1;
            Vb[base + (rp2 + 1) * WW + 16] = (unsigned short)(pv1 >> 16);
        }
    }
}

// ---------------- Kernel 2: fused S = QK^T (full t) + row softmax -> P bf16 ---
__global__ __launch_bounds__(256) void qks_kernel(
    const unsigned short* __restrict__ Qb, const unsigned short* __restrict__ Kb,
    unsigned short* __restrict__ Pb)
{
    const int o    = blockIdx.x;
    const int bh   = o & 63;
    const int c0   = (o >> 6) << 4;              // 16-row tile

    __shared__ __align__(16) char smem[36864];   // Qs 4K | Ks 32K ; Ss overlays

    const int tid  = threadIdx.x;
    const int wave = tid >> 6;
    const int lane = tid & 63;
    const int lx   = lane & 15;
    const int qd   = lane >> 4;
    const int n0   = wave << 5;                  // 32-col strip per wave

    f32x4 acc0 = {0.f, 0.f, 0.f, 0.f}, acc1 = acc0;

    const unsigned short* Qp = Qb + ((size_t)bh * CH + c0) * DHEAD;
    const unsigned short* Kp = Kb + (size_t)bh * CH * DHEAD;

    const int qr = tid >> 4, qu = tid & 15;      // Q stage: one unit per thread
    const unsigned qoff = (unsigned)((qr << 8) + (qu << 4)) ^ (((unsigned)qr & 7u) << 4);

    #pragma unroll 1
    for (int chk = 0; chk < 16; ++chk) {
        const int t0 = chk << 7;
        __syncthreads();
        {
            const bf16x8 v = *(const bf16x8*)&Qp[(size_t)qr * DHEAD + t0 + qu * 8];
            *(bf16x8*)(smem + qoff) = v;
        }
        for (int i = tid; i < 2048; i += 256) {  // K: 128 rows x 16 units
            const int r = i >> 4, u = i & 15;
            const bf16x8 v = *(const bf16x8*)&Kp[(size_t)r * DHEAD + t0 + u * 8];
            const unsigned off = 4096u +
                ((unsigned)((r << 8) + (u << 4)) ^ (((unsigned)r & 7u) << 4));
            *(bf16x8*)(smem + off) = v;
        }
        __syncthreads();
        #pragma unroll
        for (int ki = 0; ki < 4; ++ki) {
            const int kcb = (ki * 32 + qd * 8) << 1;     // k byte offset
            const bf16x8 a = *(const bf16x8*)(smem +
                ((unsigned)((lx << 8) + kcb) ^ (((unsigned)lx & 7u) << 4)));
            const int r0 = n0 + lx, r1 = n0 + 16 + lx;
            const bf16x8 b0 = *(const bf16x8*)(smem + 4096u +
                ((unsigned)((r0 << 8) + kcb) ^ (((unsigned)r0 & 7u) << 4)));
            const bf16x8 b1 = *(const bf16x8*)(smem + 4096u +
                ((unsigned)((r1 << 8) + kcb) ^ (((unsigned)r1 & 7u) << 4)));
            acc0 = __builtin_amdgcn_mfma_f32_16x16x32_bf16(a, b0, acc0, 0, 0, 0);
            acc1 = __builtin_amdgcn_mfma_f32_16x16x32_bf16(a, b1, acc1, 0, 0, 0);
        }
    }

    __syncthreads();
    float* Ss = (float*)smem;                    // [16][132] f32, 8448 B
    #pragma unroll
    for (int r = 0; r < 4; ++r) {
        Ss[(qd * 4 + r) * 132 + n0 + lx]      = acc0[r];
        Ss[(qd * 4 + r) * 132 + n0 + 16 + lx] = acc1[r];
    }
    __syncthreads();

    // softmax: 16 threads per row, 8 cols each
    const int rr = tid >> 4;
    const int c8 = (tid & 15) << 3;
    f32x4 v0 = *(const f32x4*)&Ss[rr * 132 + c8];
    f32x4 v1 = *(const f32x4*)&Ss[rr * 132 + c8 + 4];
    const f32x4 sc = {0.0078125f, 0.0078125f, 0.0078125f, 0.0078125f};
    v0 *= sc; v1 *= sc;
    float m = fmaxf(fmaxf(fmaxf(v0[0], v0[1]), fmaxf(v0[2], v0[3])),
                    fmaxf(fmaxf(v1[0], v1[1]), fmaxf(v1[2], v1[3])));
    m = fmaxf(m, __shfl_xor(m, 1));
    m = fmaxf(m, __shfl_xor(m, 2));
    m = fmaxf(m, __shfl_xor(m, 4));
    m = fmaxf(m, __shfl_xor(m, 8));
    float e[8];
    #pragma unroll
    for (int j = 0; j < 4; ++j) {
        e[j]     = __expf(v0[j] - m);
        e[4 + j] = __expf(v1[j] - m);
    }
    float s = 0.f;
    #pragma unroll
    for (int j = 0; j < 8; ++j) s += e[j];
    s += __shfl_xor(s, 1);
    s += __shfl_xor(s, 2);
    s += __shfl_xor(s, 4);
    s += __shfl_xor(s, 8);
    const float inv = 1.f / s;
    bf16x8 h;
    #pragma unroll
    for (int j = 0; j < 8; ++j) h[j] = (short)f2bf(e[j] * inv);
    *(bf16x8*)&Pb[((size_t)bh * CH + c0 + rr) * CH + c8] = h;
}

// ---------------- Kernel 4: A = P V via MFMA, out At[b][p][ci] bf16 ------------
__global__ __launch_bounds__(256) void pv_mfma_kernel(
    const unsigned short* __restrict__ Pb, const unsigned short* __restrict__ Vb,
    unsigned short* __restrict__ At)
{
    const int blk = blockIdx.x;
    const int t0  = (blk & 15) << 7;
    const int bh  = blk >> 4;

    __shared__ __align__(16) char smem[69632];
    unsigned short (*Ps)[136] = (unsigned short(*)[136])smem;            // 34816 B
    unsigned short (*Vs)[136] = (unsigned short(*)[136])(smem + 34816);  // 34816 B
    float (*So)[132] = (float(*)[132])smem;                              // reused

    const int tid  = threadIdx.x;
    const int wave = tid >> 6;
    const int lane = tid & 63;
    const int lx   = lane & 15;
    const int qd   = lane >> 4;
    const int m0   = (wave & 1) * 64;      // c tile
    const int n0   = (wave >> 1) * 64;     // t tile

    const unsigned short* Pp = Pb + (size_t)bh * CH * CH;
    const unsigned short* Vp = Vb + (size_t)bh * CH * DHEAD;

    for (int i = tid; i < 2048; i += 256) {
        const int r  = i >> 4;
        const int cl = (i & 15) << 3;
        *(bf16x8*)&Ps[r][cl] = *(const bf16x8*)&Pp[(size_t)r * CH + cl];
    }
    for (int i = tid; i < 2048; i += 256) {
        const int e   = i & 127;
        const int tc8 = (i >> 7) << 3;
        const bf16x8 vv = *(const bf16x8*)&Vp[(size_t)e * DHEAD + t0 + tc8];
        #pragma unroll
        for (int j = 0; j < 8; ++j) Vs[tc8 + j][e] = (unsigned short)vv[j];
    }
    __syncthreads();

    f32x4 acc[4][4];
    #pragma unroll
    for (int mi = 0; mi < 4; ++mi)
        #pragma unroll
        for (int ni = 0; ni < 4; ++ni) acc[mi][ni] = (f32x4){0.f, 0.f, 0.f, 0.f};

    #pragma unroll
    for (int ki = 0; ki < 4; ++ki) {
        const int kc = ki * 32 + qd * 8;
        bf16x8 a[4], bv[4];
        #pragma unroll
        for (int mi = 0; mi < 4; ++mi)
            a[mi] = *(const bf16x8*)&Ps[m0 + mi * 16 + lx][kc];
        #pragma unroll
        for (int ni = 0; ni < 4; ++ni)
            bv[ni] = *(const bf16x8*)&Vs[n0 + ni * 16 + lx][kc];
        #pragma unroll
        for (int mi = 0; mi < 4; ++mi)
            #pragma unroll
            for (int ni = 0; ni < 4; ++ni)
                acc[mi][ni] = __builtin_amdgcn_mfma_f32_16x16x32_bf16(
                    a[mi], bv[ni], acc[mi][ni], 0, 0, 0);
    }

    __syncthreads();
    #pragma unroll
    for (int mi = 0; mi < 4; ++mi)
        #pragma unroll
        for (int ni = 0; ni < 4; ++ni)
            #pragma unroll
            for (int r = 0; r < 4; ++r)
                So[n0 + ni * 16 + lx][m0 + mi * 16 + qd * 4 + r] = acc[mi][ni][r];
    __syncthreads();

    const int t  = tid >> 1;
    const int ch = (tid & 1) * 64;
    const size_t orow = (((size_t)(bh >> 3) * HWSZ) + (size_t)(bh & 7) * DHEAD + t0 + t) * CH + ch;
    #pragma unroll
    for (int j = 0; j < 8; ++j) {
        const float4 f0 = *(const float4*)&So[t][ch + j * 8];
        const float4 f1 = *(const float4*)&So[t][ch + j * 8 + 4];
        bf16x8 h;
        h[0] = (short)f2bf(f0.x); h[1] = (short)f2bf(f0.y);
        h[2] = (short)f2bf(f0.z); h[3] = (short)f2bf(f0.w);
        h[4] = (short)f2bf(f1.x); h[5] = (short)f2bf(f1.y);
        h[6] = (short)f2bf(f1.z); h[7] = (short)f2bf(f1.w);
        *(bf16x8*)&At[orow + j * 8] = h;
    }
}

// ---------------- Kernel 5a: weight prep wo fp32 -> Wt[tap][co][ci] bf16 ------
__global__ __launch_bounds__(256) void wprep_kernel(
    const float* __restrict__ wo, unsigned short* __restrict__ Wt)
{
    const int i = blockIdx.x * 256 + threadIdx.x;     // 9*128*128 = 147456
    const int tap = i >> 14;
    const int rem = i & 16383;
    const int co  = rem >> 7;
    const int ci  = rem & 127;
    Wt[i] = f2bf(wo[(size_t)(co * CH + ci) * 9 + tap]);
}

// ---------------- Kernel 5b: 3x3 dense conv, no-sA version --------------------
// Activations read DIRECT from global (L2-local via XCD swizzle; 64 B/wave
// segments, each fragment reused 4x in registers). LDS = 32 KB double-buffered
// weight slices only -> 2 blocks/CU co-resident (round-5's 160 KB = 1 block/CU
// exposed all 18 barrier drains).
__global__ __launch_bounds__(512, 4) void conv3x3_mfma_kernel(
    const unsigned short* __restrict__ At, const unsigned short* __restrict__ Wt,
    const float* __restrict__ bo, float* __restrict__ out)
{
    __shared__ __align__(16) char smem[32768];    // sW 2 x 16384

    const int w    = ((blockIdx.x & 7) << 6) | (blockIdx.x >> 3);
    const int yp   = w & 63;
    const int b    = w >> 6;
    const int y0   = yp << 1;

    const int tid  = threadIdx.x;
    const int wave = tid >> 6;
    const int lane = tid & 63;
    const int lx   = lane & 15;
    const int qd   = lane >> 4;
    const int m0   = (wave & 1) << 6;       // co half
    const int n0   = (wave >> 1) << 6;      // px quarter
    const int rsel = n0 >> 7;               // output row within pair (0/1)
    const int xb   = n0 & 64;               // x base within row

    const int j0 = tid, j1 = tid + 512;     // weight 16B-unit indices (0..1023)
    const int co0 = j0 >> 3, cu0 = j0 & 7;
    const int co1 = j1 >> 3, cu1 = j1 & 7;
    const unsigned swo0 = (unsigned)((co0 * 128 + cu0 * 16) ^ ((co0 & 7) << 4));
    const unsigned swo1 = (unsigned)((co1 * 128 + cu1 * 16) ^ ((co1 & 7) << 4));

    // prologue: slice 0 (tap0,kh0) -> buf0; then issue slice-1 loads
    float4 nwa = *(const float4*)&Wt[(size_t)co0 * 128 + cu0 * 8];
    float4 nwb = *(const float4*)&Wt[(size_t)co1 * 128 + cu1 * 8];
    *(float4*)(smem + swo0) = nwa;
    *(float4*)(smem + swo1) = nwb;
    nwa = *(const float4*)&Wt[(size_t)co0 * 128 + 64 + cu0 * 8];
    nwb = *(const float4*)&Wt[(size_t)co1 * 128 + 64 + cu1 * 8];

    f32x4 acc[4][4];
    #pragma unroll
    for (int mi = 0; mi < 4; ++mi) {
        f32x4 bv;
        #pragma unroll
        for (int r = 0; r < 4; ++r) bv[r] = bo[m0 + mi * 16 + qd * 4 + r];
        #pragma unroll
        for (int ni = 0; ni < 4; ++ni) acc[mi][ni] = bv;
    }

    const unsigned short* Ab = At + (size_t)b * HWSZ * CH;

    __syncthreads();

    #pragma unroll 1
    for (int s = 0; s < 18; ++s) {
        const int tap = s >> 1;
        const int dy  = (tap * 11) >> 5;        // tap/3
        const int txc = tap - dy * 3;           // tap%3
        const int kh  = s & 1;
        const int gy  = y0 - 1 + rsel + dy;
        const bool rok = (unsigned)gy < HH;
        const unsigned short* Arow = Ab + (size_t)gy * (WW * CH);
        const unsigned wbase = (unsigned)(s & 1) * 16384u;
        const int cis = kh * 64 + qd * 8;       // ci short-base (ks adds 32)

        #pragma unroll
        for (int ks = 0; ks < 2; ++ks) {
            const int wkb = ks * 64 + qd * 16;  // ci-byte in sW slice
            bf16x8 a[4], bfr[4];
            #pragma unroll
            for (int mi = 0; mi < 4; ++mi) {
                const int co = m0 + mi * 16 + lx;
                a[mi] = *(const bf16x8*)(smem + wbase +
                        (unsigned)((co * 128 + wkb) ^ ((co & 7) << 4)));
            }
            #pragma unroll
            for (int ni = 0; ni < 4; ++ni) {
                const int xx = xb + ni * 16 + lx + txc - 1;   // -1..128
                bfr[ni] = (bf16x8){0, 0, 0, 0, 0, 0, 0, 0};
                if (rok && (unsigned)xx < WW)
                    bfr[ni] = *(const bf16x8*)&Arow[(size_t)xx * CH + cis + ks * 32];
            }
            #pragma unroll
            for (int mi = 0; mi < 4; ++mi)
                #pragma unroll
                for (int ni = 0; ni < 4; ++ni)
                    acc[mi][ni] = __builtin_amdgcn_mfma_f32_16x16x32_bf16(
                        a[mi], bfr[ni], acc[mi][ni], 0, 0, 0);
        }
        if (s < 17) {
            const unsigned nb = (unsigned)((s + 1) & 1) * 16384u;
            *(float4*)(smem + nb + swo0) = nwa;     // slice s+1
            *(float4*)(smem + nb + swo1) = nwb;
            if (s < 16) {
                const int s2 = s + 2;
                const size_t gb = (size_t)(s2 >> 1) * 16384 + (s2 & 1) * 64;
                nwa = *(const float4*)&Wt[gb + co0 * 128 + cu0 * 8];
                nwb = *(const float4*)&Wt[gb + co1 * 128 + cu1 * 8];
            }
        }
        __syncthreads();
    }

    const int gy = y0 + rsel;
    const size_t obase = (size_t)b * CH * HWSZ + (size_t)gy * WW + xb;
    #pragma unroll
    for (int mi = 0; mi < 4; ++mi) {
        #pragma unroll
        for (int r = 0; r < 4; ++r) {
            const int co = m0 + mi * 16 + qd * 4 + r;
            float* orow = out + obase + (size_t)co * HWSZ;
            #pragma unroll
            for (int ni = 0; ni < 4; ++ni)
                orow[ni * 16 + lx] = acc[mi][ni][r];
        }
    }
}

extern "C" void kernel_launch(void* const* d_in, const int* in_sizes, int n_in,
                              void* d_out, int out_size, void* d_ws, size_t ws_size,
                              hipStream_t stream)
{
    const float* x  = (const float*)d_in[0];
    const float* wq = (const float*)d_in[1];
    const float* bq = (const float*)d_in[2];
    const float* wk = (const float*)d_in[3];
    const float* bk = (const float*)d_in[4];
    const float* wv = (const float*)d_in[5];
    const float* bv = (const float*)d_in[6];
    const float* wo = (const float*)d_in[7];
    const float* bo = (const float*)d_in[8];

    char* ws = (char*)d_ws;
    unsigned short* Qb    = (unsigned short*)(ws);                        // 32 MiB
    unsigned short* Kb    = (unsigned short*)(ws + (size_t)33554432);     // 32 MiB
    unsigned short* Vb    = (unsigned short*)(ws + (size_t)67108864);     // 32 MiB
    unsigned short* Pb    = (unsigned short*)(ws + (size_t)134217728);    // 2 MiB
    unsigned short* At    = (unsigned short*)(ws + (size_t)136314880);    // 32 MiB
    unsigned short* Wt    = (unsigned short*)(ws + (size_t)169869312);    // 288 KiB
    _Float16*       Tp    = (_Float16*)      (ws + (size_t)100663296);    // 3.5 MiB

    toeplitz_prep_kernel<<<864, 256, 0, stream>>>(wq, wk, wv, Tp);
    dwconv_qkv_mfma_kernel<<<BATCH * CH, 256, 0, stream>>>(x, bq, bk, bv, Tp, Qb, Kb, Vb);
    wprep_kernel<<<576, 256, 0, stream>>>(wo, Wt);
    qks_kernel<<<512, 256, 0, stream>>>(Qb, Kb, Pb);
    pv_mfma_kernel<<<64 * 16, 256, 0, stream>>>(Pb, Vb, At);
    conv3x3_mfma_kernel<<<BATCH * 64, 512, 0, stream>>>(At, Wt, bo, (float*)d_out);
}

// Round 7
// 278.264 us; speedup vs baseline: 1.1127x; 1.1127x over previous
//
#include <hip/hip_runtime.h>

#define BATCH 8
#define CH 128
#define HH 128
#define WW 128
#define HWSZ 16384
#define NHEADS 8
#define DHEAD 2048

typedef short bf16x8 __attribute__((ext_vector_type(8)));
typedef short bf16x4v __attribute__((ext_vector_type(4)));
typedef float f32x4 __attribute__((ext_vector_type(4)));
typedef float f32x2 __attribute__((ext_vector_type(2)));
typedef _Float16 f16x8 __attribute__((ext_vector_type(8)));
typedef _Float16 f16x4 __attribute__((ext_vector_type(4)));

static __device__ inline unsigned short f2bf(float f) {
    unsigned u = __builtin_bit_cast(unsigned, f);
    u += 0x7fff + ((u >> 16) & 1);          // round-to-nearest-even
    return (unsigned short)(u >> 16);
}

// ---------------- Kernel 0: build Toeplitz fragments for dwconv MFMA ----------
__global__ __launch_bounds__(256) void toeplitz_prep_kernel(
    const float* __restrict__ wq, const float* __restrict__ wk,
    const float* __restrict__ wv, _Float16* __restrict__ Tp)
{
    const int g = blockIdx.x * 256 + threadIdx.x;   // 128*27*64 = 221184
    const int c    = g / 1728;                      // 27*64
    const int rem  = g - c * 1728;
    const int m    = rem >> 6;
    const int lane = rem & 63;
    const int conv = m / 9;
    const int dy   = m - conv * 9;
    const float* w = (conv == 0) ? wq : ((conv == 1) ? wk : wv);
    const int j    = lane & 15;
    const int kb   = (lane >> 4) << 3;
    f16x8 h;
    #pragma unroll
    for (int e = 0; e < 8; ++e) {
        const int d = kb + e - j;
        h[e] = (d >= 0 && d <= 8) ? (_Float16)w[c * 81 + dy * 9 + d]
                                  : (_Float16)0.f;
    }
    *(f16x8*)&Tp[(size_t)g * 8] = h;
}

// ---------------- Kernel 1: depthwise 9x9 conv -> Q,K,V via MFMA Toeplitz -----
// Toeplitz fragments in LDS (27 KB, staged once): rounds 5/6 showed the
// compiler never keeps 27 fragments (108 VGPR) register-resident (VGPR=88/
// refetch-per-iter stall). LDS reads (3 x ds_read_b128 per dy) + ~70 VGPR
// -> 2 blocks/CU, MFMA-dominated loop.
__global__ __launch_bounds__(256) void dwconv_qkv_mfma_kernel(
    const float* __restrict__ x,
    const float* __restrict__ bq, const float* __restrict__ bk,
    const float* __restrict__ bv,
    const _Float16* __restrict__ Tp,
    unsigned short* __restrict__ Qb, unsigned short* __restrict__ Kb,
    unsigned short* __restrict__ Vb)
{
    const int bc = blockIdx.x;
    const int b  = bc >> 7;
    const int c  = bc & (CH - 1);

    __shared__ _Float16 img[136][144];   // [y+4][x+4], zero halo, 39168 B
    __shared__ _Float16 tps[13824];      // 27 fragments x 64 lanes x 8, 27648 B

    const int tid  = threadIdx.x;
    const int wave = tid >> 6;
    const int lane = tid & 63;
    const int lx   = lane & 15;
    const int qd   = lane >> 4;

    // stage Toeplitz table (coalesced 16B units)
    {
        const _Float16* tg = Tp + (size_t)c * 13824;
        for (int i = tid; i < 1728; i += 256)
            *(f16x8*)&tps[i * 8] = *(const f16x8*)&tg[i * 8];
    }
    // zero halo + fill image
    {
        f16x8 z = {0, 0, 0, 0, 0, 0, 0, 0};
        _Float16* flat = &img[0][0];
        for (int i = tid; i < 2448; i += 256)       // 136*144/8
            *(f16x8*)&flat[i * 8] = z;
    }
    __syncthreads();
    const float* xp = x + (size_t)bc * HWSZ;
    for (int i = tid; i < 4096; i += 256) {
        const float4 v = *(const float4*)&xp[i * 4];
        const int y  = i >> 5;
        const int xc = (i & 31) << 2;
        f16x4 h = {(_Float16)v.x, (_Float16)v.y, (_Float16)v.z, (_Float16)v.w};
        *(f16x4*)&img[y + 4][xc + 4] = h;
    }
    __syncthreads();

    const float bqv = bq[c], bkv = bk[c], bvv = bv[c];
    const _Float16* tl = tps + lane * 8;            // lane's slot in each fragment

    #pragma unroll 1
    for (int t = 0; t < 8; ++t) {
        const int sg = t * 4 + wave;                // 32 supergroups / block
        const int yg = sg >> 2;
        const int y0 = yg << 4;
        const int x0 = (sg & 3) << 5;

        f32x4 aq0 = {bqv, bqv, bqv, bqv}, aq1 = aq0;
        f32x4 ak0 = {bkv, bkv, bkv, bkv}, ak1 = ak0;
        f32x4 av0 = {bvv, bvv, bvv, bvv}, av1 = av0;

        const _Float16* rp = &img[y0 + lx][x0 + (qd << 3)];
        #pragma unroll
        for (int dy = 0; dy < 9; ++dy) {
            const f16x8 a0 = *(const f16x8*)rp;
            const f16x8 a1 = *(const f16x8*)(rp + 16);
            rp += 144;
            const f16x8 bq_ = *(const f16x8*)(tl + dy * 512);
            const f16x8 bk_ = *(const f16x8*)(tl + (9 + dy) * 512);
            const f16x8 bv_ = *(const f16x8*)(tl + (18 + dy) * 512);
            aq0 = __builtin_amdgcn_mfma_f32_16x16x32_f16(a0, bq_, aq0, 0, 0, 0);
            aq1 = __builtin_amdgcn_mfma_f32_16x16x32_f16(a1, bq_, aq1, 0, 0, 0);
            ak0 = __builtin_amdgcn_mfma_f32_16x16x32_f16(a0, bk_, ak0, 0, 0, 0);
            ak1 = __builtin_amdgcn_mfma_f32_16x16x32_f16(a1, bk_, ak1, 0, 0, 0);
            av0 = __builtin_amdgcn_mfma_f32_16x16x32_f16(a0, bv_, av0, 0, 0, 0);
            av1 = __builtin_amdgcn_mfma_f32_16x16x32_f16(a1, bv_, av1, 0, 0, 0);
        }

        // C layout: lane holds D[y = qd*4+r][x = lx]; t = (y&15)*128 + x, head = yg
        const size_t base = ((size_t)(b * 8 + yg) * CH + c) * DHEAD
                          + (size_t)(qd << 2) * WW + x0 + lx;
        #pragma unroll
        for (int r = 0; r < 4; ++r) {
            Qb[base + r * WW]      = f2bf(aq0[r]);
            Qb[base + r * WW + 16] = f2bf(aq1[r]);
            Kb[base + r * WW]      = f2bf(ak0[r]);
            Kb[base + r * WW + 16] = f2bf(ak1[r]);
            Vb[base + r * WW]      = f2bf(av0[r]);
            Vb[base + r * WW + 16] = f2bf(av1[r]);
        }
    }
}

// ---------------- Kernel 2: fused S = QK^T (full t) + row softmax -> P bf16 ---
__global__ __launch_bounds__(256) void qks_kernel(
    const unsigned short* __restrict__ Qb, const unsigned short* __restrict__ Kb,
    unsigned short* __restrict__ Pb)
{
    const int o    = blockIdx.x;
    const int bh   = o & 63;
    const int c0   = (o >> 6) << 4;              // 16-row tile

    __shared__ __align__(16) char smem[36864];   // Qs 4K | Ks 32K ; Ss overlays

    const int tid  = threadIdx.x;
    const int wave = tid >> 6;
    const int lane = tid & 63;
    const int lx   = lane & 15;
    const int qd   = lane >> 4;
    const int n0   = wave << 5;                  // 32-col strip per wave

    f32x4 acc0 = {0.f, 0.f, 0.f, 0.f}, acc1 = acc0;

    const unsigned short* Qp = Qb + ((size_t)bh * CH + c0) * DHEAD;
    const unsigned short* Kp = Kb + (size_t)bh * CH * DHEAD;

    const int qr = tid >> 4, qu = tid & 15;      // Q stage: one unit per thread
    const unsigned qoff = (unsigned)((qr << 8) + (qu << 4)) ^ (((unsigned)qr & 7u) << 4);

    #pragma unroll 1
    for (int chk = 0; chk < 16; ++chk) {
        const int t0 = chk << 7;
        __syncthreads();
        {
            const bf16x8 v = *(const bf16x8*)&Qp[(size_t)qr * DHEAD + t0 + qu * 8];
            *(bf16x8*)(smem + qoff) = v;
        }
        for (int i = tid; i < 2048; i += 256) {  // K: 128 rows x 16 units
            const int r = i >> 4, u = i & 15;
            const bf16x8 v = *(const bf16x8*)&Kp[(size_t)r * DHEAD + t0 + u * 8];
            const unsigned off = 4096u +
                ((unsigned)((r << 8) + (u << 4)) ^ (((unsigned)r & 7u) << 4));
            *(bf16x8*)(smem + off) = v;
        }
        __syncthreads();
        #pragma unroll
        for (int ki = 0; ki < 4; ++ki) {
            const int kcb = (ki * 32 + qd * 8) << 1;     // k byte offset
            const bf16x8 a = *(const bf16x8*)(smem +
                ((unsigned)((lx << 8) + kcb) ^ (((unsigned)lx & 7u) << 4)));
            const int r0 = n0 + lx, r1 = n0 + 16 + lx;
            const bf16x8 b0 = *(const bf16x8*)(smem + 4096u +
                ((unsigned)((r0 << 8) + kcb) ^ (((unsigned)r0 & 7u) << 4)));
            const bf16x8 b1 = *(const bf16x8*)(smem + 4096u +
                ((unsigned)((r1 << 8) + kcb) ^ (((unsigned)r1 & 7u) << 4)));
            acc0 = __builtin_amdgcn_mfma_f32_16x16x32_bf16(a, b0, acc0, 0, 0, 0);
            acc1 = __builtin_amdgcn_mfma_f32_16x16x32_bf16(a, b1, acc1, 0, 0, 0);
        }
    }

    __syncthreads();
    float* Ss = (float*)smem;                    // [16][132] f32, 8448 B
    #pragma unroll
    for (int r = 0; r < 4; ++r) {
        Ss[(qd * 4 + r) * 132 + n0 + lx]      = acc0[r];
        Ss[(qd * 4 + r) * 132 + n0 + 16 + lx] = acc1[r];
    }
    __syncthreads();

    // softmax: 16 threads per row, 8 cols each
    const int rr = tid >> 4;
    const int c8 = (tid & 15) << 3;
    f32x4 v0 = *(const f32x4*)&Ss[rr * 132 + c8];
    f32x4 v1 = *(const f32x4*)&Ss[rr * 132 + c8 + 4];
    const f32x4 sc = {0.0078125f, 0.0078125f, 0.0078125f, 0.0078125f};
    v0 *= sc; v1 *= sc;
    float m = fmaxf(fmaxf(fmaxf(v0[0], v0[1]), fmaxf(v0[2], v0[3])),
                    fmaxf(fmaxf(v1[0], v1[1]), fmaxf(v1[2], v1[3])));
    m = fmaxf(m, __shfl_xor(m, 1));
    m = fmaxf(m, __shfl_xor(m, 2));
    m = fmaxf(m, __shfl_xor(m, 4));
    m = fmaxf(m, __shfl_xor(m, 8));
    float e[8];
    #pragma unroll
    for (int j = 0; j < 4; ++j) {
        e[j]     = __expf(v0[j] - m);
        e[4 + j] = __expf(v1[j] - m);
    }
    float s = 0.f;
    #pragma unroll
    for (int j = 0; j < 8; ++j) s += e[j];
    s += __shfl_xor(s, 1);
    s += __shfl_xor(s, 2);
    s += __shfl_xor(s, 4);
    s += __shfl_xor(s, 8);
    const float inv = 1.f / s;
    bf16x8 h;
    #pragma unroll
    for (int j = 0; j < 8; ++j) h[j] = (short)f2bf(e[j] * inv);
    *(bf16x8*)&Pb[((size_t)bh * CH + c0 + rr) * CH + c8] = h;
}

// ---------------- Kernel 4: A = P V via MFMA, out At[b][p][ci] bf16 ------------
__global__ __launch_bounds__(256) void pv_mfma_kernel(
    const unsigned short* __restrict__ Pb, const unsigned short* __restrict__ Vb,
    unsigned short* __restrict__ At)
{
    const int blk = blockIdx.x;
    const int t0  = (blk & 15) << 7;
    const int bh  = blk >> 4;

    __shared__ __align__(16) char smem[69632];
    unsigned short (*Ps)[136] = (unsigned short(*)[136])smem;            // 34816 B
    unsigned short (*Vs)[136] = (unsigned short(*)[136])(smem + 34816);  // 34816 B
    float (*So)[132] = (float(*)[132])smem;                              // reused

    const int tid  = threadIdx.x;
    const int wave = tid >> 6;
    const int lane = tid & 63;
    const int lx   = lane & 15;
    const int qd   = lane >> 4;
    const int m0   = (wave & 1) * 64;      // c tile
    const int n0   = (wave >> 1) * 64;     // t tile

    const unsigned short* Pp = Pb + (size_t)bh * CH * CH;
    const unsigned short* Vp = Vb + (size_t)bh * CH * DHEAD;

    for (int i = tid; i < 2048; i += 256) {
        const int r  = i >> 4;
        const int cl = (i & 15) << 3;
        *(bf16x8*)&Ps[r][cl] = *(const bf16x8*)&Pp[(size_t)r * CH + cl];
    }
    for (int i = tid; i < 2048; i += 256) {
        const int e   = i & 127;
        const int tc8 = (i >> 7) << 3;
        const bf16x8 vv = *(const bf16x8*)&Vp[(size_t)e * DHEAD + t0 + tc8];
        #pragma unroll
        for (int j = 0; j < 8; ++j) Vs[tc8 + j][e] = (unsigned short)vv[j];
    }
    __syncthreads();

    f32x4 acc[4][4];
    #pragma unroll
    for (int mi = 0; mi < 4; ++mi)
        #pragma unroll
        for (int ni = 0; ni < 4; ++ni) acc[mi][ni] = (f32x4){0.f, 0.f, 0.f, 0.f};

    #pragma unroll
    for (int ki = 0; ki < 4; ++ki) {
        const int kc = ki * 32 + qd * 8;
        bf16x8 a[4], bv[4];
        #pragma unroll
        for (int mi = 0; mi < 4; ++mi)
            a[mi] = *(const bf16x8*)&Ps[m0 + mi * 16 + lx][kc];
        #pragma unroll
        for (int ni = 0; ni < 4; ++ni)
            bv[ni] = *(const bf16x8*)&Vs[n0 + ni * 16 + lx][kc];
        #pragma unroll
        for (int mi = 0; mi < 4; ++mi)
            #pragma unroll
            for (int ni = 0; ni < 4; ++ni)
                acc[mi][ni] = __builtin_amdgcn_mfma_f32_16x16x32_bf16(
                    a[mi], bv[ni], acc[mi][ni], 0, 0, 0);
    }

    __syncthreads();
    #pragma unroll
    for (int mi = 0; mi < 4; ++mi)
        #pragma unroll
        for (int ni = 0; ni < 4; ++ni)
            #pragma unroll
            for (int r = 0; r < 4; ++r)
                So[n0 + ni * 16 + lx][m0 + mi * 16 + qd * 4 + r] = acc[mi][ni][r];
    __syncthreads();

    const int t  = tid >> 1;
    const int ch = (tid & 1) * 64;
    const size_t orow = (((size_t)(bh >> 3) * HWSZ) + (size_t)(bh & 7) * DHEAD + t0 + t) * CH + ch;
    #pragma unroll
    for (int j = 0; j < 8; ++j) {
        const float4 f0 = *(const float4*)&So[t][ch + j * 8];
        const float4 f1 = *(const float4*)&So[t][ch + j * 8 + 4];
        bf16x8 h;
        h[0] = (short)f2bf(f0.x); h[1] = (short)f2bf(f0.y);
        h[2] = (short)f2bf(f0.z); h[3] = (short)f2bf(f0.w);
        h[4] = (short)f2bf(f1.x); h[5] = (short)f2bf(f1.y);
        h[6] = (short)f2bf(f1.z); h[7] = (short)f2bf(f1.w);
        *(bf16x8*)&At[orow + j * 8] = h;
    }
}

// ---------------- Kernel 5a: weight prep wo fp32 -> Wt[tap][co][ci] bf16 ------
__global__ __launch_bounds__(256) void wprep_kernel(
    const float* __restrict__ wo, unsigned short* __restrict__ Wt)
{
    const int i = blockIdx.x * 256 + threadIdx.x;     // 9*128*128 = 147456
    const int tap = i >> 14;
    const int rem = i & 16383;
    const int co  = rem >> 7;
    const int ci  = rem & 127;
    Wt[i] = f2bf(wo[(size_t)(co * CH + ci) * 9 + tap]);
}

// ---------------- Kernel 5b: 3x3 dense conv (round-3 body, measured 59 us) ----
__global__ __launch_bounds__(512, 2) void conv3x3_mfma_kernel(
    const unsigned short* __restrict__ At, const unsigned short* __restrict__ Wt,
    const float* __restrict__ bo, float* __restrict__ out)
{
    __shared__ __align__(16) char smem[149504];       // sA 133120 + sW 16384

    const int w    = ((blockIdx.x & 7) << 6) | (blockIdx.x >> 3);
    const int yp   = w & 63;
    const int b    = w >> 6;
    const int y0   = yp << 1;

    const int tid  = threadIdx.x;
    const int wave = tid >> 6;
    const int lane = tid & 63;
    const int lx   = lane & 15;
    const int qd   = lane >> 4;
    const int m0   = (wave & 1) << 6;       // co half
    const int n0   = (wave >> 1) << 6;      // px quarter
    const int rsel = n0 >> 7;               // output row within pair (0/1)
    const int xb   = n0 & 64;               // x base within row

    const int j0 = tid, j1 = tid + 512;     // weight 16B-unit indices (0..1023)
    const int co0 = j0 >> 3, cu0 = j0 & 7;
    const int co1 = j1 >> 3, cu1 = j1 & 7;
    const unsigned swo0 = (unsigned)((co0 * 128 + cu0 * 16) ^ ((co0 & 7) << 4)) + 133120u;
    const unsigned swo1 = (unsigned)((co1 * 128 + cu1 * 16) ^ ((co1 & 7) << 4)) + 133120u;

    float4 nwa = *(const float4*)&Wt[(size_t)co0 * 128 + cu0 * 8];
    float4 nwb = *(const float4*)&Wt[(size_t)co1 * 128 + cu1 * 8];

    const size_t abase = (size_t)b * HWSZ * CH;
    if (tid < 128) {
        const int r  = tid >> 5;
        const int cu = tid & 31;
        const int xp = (cu & 16) ? 129 : 0;
        const int u  = cu & 15;
        const unsigned off = (unsigned)(r * 33280 + xp * 256 + u * 16) ^ (((unsigned)xp & 7u) << 4);
        *(float4*)(smem + off) = make_float4(0.f, 0.f, 0.f, 0.f);
    }
    for (int i = tid; i < 8192; i += 512) {
        const int r   = i >> 11;
        const int rem = i & 2047;
        const int xx  = rem >> 4;
        const int u   = rem & 15;
        const int gy  = y0 - 1 + r;
        float4 v = make_float4(0.f, 0.f, 0.f, 0.f);
        if ((unsigned)gy < HH)
            v = *(const float4*)&At[abase + (size_t)gy * WW * CH + xx * CH + u * 8];
        const int xp = xx + 1;
        const unsigned off = (unsigned)(r * 33280 + xp * 256 + u * 16) ^ (((unsigned)xp & 7u) << 4);
        *(float4*)(smem + off) = v;
    }
    *(float4*)(smem + swo0) = nwa;
    *(float4*)(smem + swo1) = nwb;
    nwa = *(const float4*)&Wt[(size_t)co0 * 128 + 64 + cu0 * 8];   // tap0, kh1
    nwb = *(const float4*)&Wt[(size_t)co1 * 128 + 64 + cu1 * 8];

    f32x4 acc[4][4];
    #pragma unroll
    for (int mi = 0; mi < 4; ++mi) {
        f32x4 bv;
        #pragma unroll
        for (int r = 0; r < 4; ++r) bv[r] = bo[m0 + mi * 16 + qd * 4 + r];
        #pragma unroll
        for (int ni = 0; ni < 4; ++ni) acc[mi][ni] = bv;
    }

    __syncthreads();

    #pragma unroll 1
    for (int s = 0; s < 18; ++s) {
        const int tap = s >> 1;
        const int dy  = (tap * 11) >> 5;        // tap/3
        const int txc = tap - dy * 3;           // tap%3
        const int kh  = s & 1;
        const int ra  = rsel + dy;

        #pragma unroll
        for (int ks = 0; ks < 2; ++ks) {
            const int wkb = ks * 64 + qd * 16;            // ci-byte in sW slice
            const int akb = kh * 128 + ks * 64 + qd * 16; // ci-byte in sA row
            bf16x8 a[4], bfr[4];
            #pragma unroll
            for (int mi = 0; mi < 4; ++mi) {
                const int co = m0 + mi * 16 + lx;
                a[mi] = *(const bf16x8*)(smem + 133120u +
                        (unsigned)((co * 128 + wkb) ^ ((co & 7) << 4)));
            }
            #pragma unroll
            for (int ni = 0; ni < 4; ++ni) {
                const int xp = xb + ni * 16 + lx + txc;   // 0..129
                const unsigned off = (unsigned)(ra * 33280 + xp * 256 + akb)
                                   ^ (((unsigned)xp & 7u) << 4);
                bfr[ni] = *(const bf16x8*)(smem + off);
            }
            #pragma unroll
            for (int mi = 0; mi < 4; ++mi)
                #pragma unroll
                for (int ni = 0; ni < 4; ++ni)
                    acc[mi][ni] = __builtin_amdgcn_mfma_f32_16x16x32_bf16(
                        a[mi], bfr[ni], acc[mi][ni], 0, 0, 0);
        }
        __syncthreads();
        if (s < 17) {
            *(float4*)(smem + swo0) = nwa;     // slice s+1 into sW
            *(float4*)(smem + swo1) = nwb;
            if (s < 16) {
                const int s2 = s + 2;
                const size_t gb = (size_t)(s2 >> 1) * 16384 + (s2 & 1) * 64;
                nwa = *(const float4*)&Wt[gb + co0 * 128 + cu0 * 8];
                nwb = *(const float4*)&Wt[gb + co1 * 128 + cu1 * 8];
            }
            __syncthreads();
        }
    }

    const int gy = y0 + rsel;
    const size_t obase = (size_t)b * CH * HWSZ + (size_t)gy * WW + xb;
    #pragma unroll
    for (int mi = 0; mi < 4; ++mi) {
        #pragma unroll
        for (int r = 0; r < 4; ++r) {
            const int co = m0 + mi * 16 + qd * 4 + r;
            float* orow = out + obase + (size_t)co * HWSZ;
            #pragma unroll
            for (int ni = 0; ni < 4; ++ni)
                orow[ni * 16 + lx] = acc[mi][ni][r];
        }
    }
}

extern "C" void kernel_launch(void* const* d_in, const int* in_sizes, int n_in,
                              void* d_out, int out_size, void* d_ws, size_t ws_size,
                              hipStream_t stream)
{
    const float* x  = (const float*)d_in[0];
    const float* wq = (const float*)d_in[1];
    const float* bq = (const float*)d_in[2];
    const float* wk = (const float*)d_in[3];
    const float* bk = (const float*)d_in[4];
    const float* wv = (const float*)d_in[5];
    const float* bv = (const float*)d_in[6];
    const float* wo = (const float*)d_in[7];
    const float* bo = (const float*)d_in[8];

    char* ws = (char*)d_ws;
    unsigned short* Qb    = (unsigned short*)(ws);                        // 32 MiB
    unsigned short* Kb    = (unsigned short*)(ws + (size_t)33554432);     // 32 MiB
    unsigned short* Vb    = (unsigned short*)(ws + (size_t)67108864);     // 32 MiB
    unsigned short* Pb    = (unsigned short*)(ws + (size_t)134217728);    // 2 MiB
    unsigned short* At    = (unsigned short*)(ws + (size_t)136314880);    // 32 MiB
    unsigned short* Wt    = (unsigned short*)(ws + (size_t)169869312);    // 288 KiB
    _Float16*       Tp    = (_Float16*)      (ws + (size_t)100663296);    // 3.5 MiB

    toeplitz_prep_kernel<<<864, 256, 0, stream>>>(wq, wk, wv, Tp);
    dwconv_qkv_mfma_kernel<<<BATCH * CH, 256, 0, stream>>>(x, bq, bk, bv, Tp, Qb, Kb, Vb);
    wprep_kernel<<<576, 256, 0, stream>>>(wo, Wt);
    qks_kernel<<<512, 256, 0, stream>>>(Qb, Kb, Pb);
    pv_mfma_kernel<<<64 * 16, 256, 0, stream>>>(Pb, Vb, At);
    conv3x3_mfma_kernel<<<BATCH * 64, 512, 0, stream>>>(At, Wt, bo, (float*)d_out);
}